// Round 1
// baseline (1001.449 us; speedup 1.0000x reference)
//
#include <hip/hip_runtime.h>

// ---- problem constants (B=4, S=2048, H=4096, O=4096, E=8) ----
#define NTOK 8192     // B*S
#define H    4096
#define O    4096
#define NEXP 8

typedef __bf16 bf16x8 __attribute__((ext_vector_type(8)));
typedef float  f32x4  __attribute__((ext_vector_type(4)));

typedef const __attribute__((address_space(1))) void* gas_ptr;
typedef __attribute__((address_space(3))) void*       las_ptr;

__device__ __forceinline__ void gload_lds16(const void* g, void* l) {
  __builtin_amdgcn_global_load_lds((gas_ptr)g, (las_ptr)l, 16, 0, 0);
}

__device__ __forceinline__ unsigned short f2bf(float f) {
  unsigned int u = __builtin_bit_cast(unsigned int, f);
  unsigned int r = (u + 0x7FFFu + ((u >> 16) & 1u)) >> 16;  // RNE
  return (unsigned short)r;
}

// ---------------- sign(weight) -> bf16 {+1,-1,0} ----------------
__global__ __launch_bounds__(256) void sign_kernel(const float* __restrict__ w,
                                                   unsigned short* __restrict__ wb) {
  const int n4 = (O * H) / 4;
  int i = blockIdx.x * blockDim.x + threadIdx.x;
  const int stride = gridDim.x * blockDim.x;
  for (; i < n4; i += stride) {
    float4 v = reinterpret_cast<const float4*>(w)[i];
    ushort4 o;
    o.x = v.x > 0.f ? 0x3F80u : (v.x < 0.f ? 0xBF80u : 0u);
    o.y = v.y > 0.f ? 0x3F80u : (v.y < 0.f ? 0xBF80u : 0u);
    o.z = v.z > 0.f ? 0x3F80u : (v.z < 0.f ? 0xBF80u : 0u);
    o.w = v.w > 0.f ? 0x3F80u : (v.w < 0.f ? 0xBF80u : 0u);
    reinterpret_cast<ushort4*>(wb)[i] = o;
  }
}

// ---------------- routing + input-scale + bf16 quant ----------------
// one block (256 thr) per token row
__global__ __launch_bounds__(256) void prep_kernel(
    const float* __restrict__ x,        // [NTOK][H]
    const float* __restrict__ gw,       // [E][H]
    const float* __restrict__ ics,      // [E][H]
    unsigned short* __restrict__ xs,    // [NTOK][H] bf16 bits
    float* __restrict__ routing) {      // [NTOK][E]
  __shared__ float sRed[4 * NEXP];
  __shared__ float sR[NEXP];
  const int row = blockIdx.x;
  const int tid = threadIdx.x;
  const float* xr = x + (size_t)row * H;

  float4 xv[4];
  float acc[NEXP];
#pragma unroll
  for (int e = 0; e < NEXP; ++e) acc[e] = 0.f;

#pragma unroll
  for (int i = 0; i < 4; ++i) {
    const int c = (tid + 256 * i) * 4;
    xv[i] = *reinterpret_cast<const float4*>(xr + c);
#pragma unroll
    for (int e = 0; e < NEXP; ++e) {
      float4 g = *reinterpret_cast<const float4*>(gw + e * H + c);
      acc[e] += xv[i].x * g.x + xv[i].y * g.y + xv[i].z * g.z + xv[i].w * g.w;
    }
  }
  // wave64 butterfly reduce
#pragma unroll
  for (int e = 0; e < NEXP; ++e) {
#pragma unroll
    for (int s = 1; s < 64; s <<= 1) acc[e] += __shfl_xor(acc[e], s);
  }
  if ((tid & 63) == 0) {
#pragma unroll
    for (int e = 0; e < NEXP; ++e) sRed[(tid >> 6) * NEXP + e] = acc[e];
  }
  __syncthreads();
  if (tid == 0) {
    float l[NEXP];
    float mx = -1e30f;
#pragma unroll
    for (int e = 0; e < NEXP; ++e) {
      l[e] = sRed[e] + sRed[NEXP + e] + sRed[2 * NEXP + e] + sRed[3 * NEXP + e];
      mx = fmaxf(mx, l[e]);
    }
    float s = 0.f;
#pragma unroll
    for (int e = 0; e < NEXP; ++e) { l[e] = __expf(l[e] - mx); s += l[e]; }
    const float inv = 1.f / s;
#pragma unroll
    for (int e = 0; e < NEXP; ++e) {
      const float r = l[e] * inv;
      sR[e] = r;
      routing[(size_t)row * NEXP + e] = r;
    }
  }
  __syncthreads();
  float r[NEXP];
#pragma unroll
  for (int e = 0; e < NEXP; ++e) r[e] = sR[e];

#pragma unroll
  for (int i = 0; i < 4; ++i) {
    const int c = (tid + 256 * i) * 4;
    float ax = 0.f, ay = 0.f, az = 0.f, aw = 0.f;
#pragma unroll
    for (int e = 0; e < NEXP; ++e) {
      float4 g = *reinterpret_cast<const float4*>(ics + e * H + c);
      ax += r[e] * g.x; ay += r[e] * g.y; az += r[e] * g.z; aw += r[e] * g.w;
    }
    ushort4 o;
    o.x = f2bf(xv[i].x * ax);
    o.y = f2bf(xv[i].y * ay);
    o.z = f2bf(xv[i].z * az);
    o.w = f2bf(xv[i].w * aw);
    *reinterpret_cast<ushort4*>(xs + (size_t)row * H + c) = o;
  }
}

// ---------------- main GEMM: C = xs @ wb^T, epilogue *out_scale + bias ----------------
#define TILE 128
#define BK   32
#define NBM  (NTOK / TILE)   // 64
#define NBN  (O / TILE)      // 32

__global__ __launch_bounds__(256) void gemm_kernel(
    const unsigned short* __restrict__ A,   // xs  [NTOK][H] bf16 bits
    const unsigned short* __restrict__ Bw,  // wb  [O][H]   bf16 bits
    const float* __restrict__ routing,      // [NTOK][E]
    const float* __restrict__ ocs,          // [E][O]
    const float* __restrict__ bias,         // [O]
    float* __restrict__ C) {                // [NTOK][O]
  __shared__ __align__(16) unsigned short sA[TILE * BK];   // [row][k] 8 KB
  __shared__ __align__(16) unsigned short sB[TILE * BK];   // [col][k] 8 KB
  __shared__ float sRout[TILE][NEXP + 1];                  // padded
  __shared__ float sOcs[NEXP][TILE];
  __shared__ float sBias[TILE];

  const int tid  = threadIdx.x;
  const int lane = tid & 63;
  const int wid  = tid >> 6;
  const int wr   = wid >> 1;   // wave row 0..1
  const int wc   = wid & 1;    // wave col 0..1

  // XCD-aware bijective swizzle (2048 blocks % 8 == 0)
  const int bid = blockIdx.x;
  const int cpx = (NBM * NBN) >> 3;
  const int swz = (bid & 7) * cpx + (bid >> 3);
  const int bm = swz / NBN, bn = swz % NBN;
  const int rowBase = bm * TILE, colBase = bn * TILE;

  // epilogue operands -> LDS (consumed after the k-loop; barriers in loop cover it)
  for (int i = tid; i < TILE * NEXP; i += 256)
    sRout[i >> 3][i & 7] = routing[(size_t)(rowBase + (i >> 3)) * NEXP + (i & 7)];
  for (int i = tid; i < NEXP * TILE; i += 256)
    sOcs[i >> 7][i & 127] = ocs[(size_t)(i >> 7) * O + colBase + (i & 127)];
  if (tid < TILE) sBias[tid] = bias[colBase + tid];

  const f32x4 fzero = {0.f, 0.f, 0.f, 0.f};
  f32x4 acc[4][4];
#pragma unroll
  for (int m = 0; m < 4; ++m)
#pragma unroll
    for (int n = 0; n < 4; ++n) acc[m][n] = fzero;

  const unsigned short* aP = A + (size_t)rowBase * H;
  const unsigned short* bP = Bw + (size_t)colBase * H;
  const int srow = tid >> 2;           // 0..63
  const int skc  = (tid & 3) << 3;     // k-chunk offset in elements

  for (int k0 = 0; k0 < H; k0 += BK) {
    // stage 128x32 A-tile + 128x32 B-tile, 16 B per lane, linear LDS
    gload_lds16(aP + (size_t)srow * H + k0 + skc, &sA[tid * 8]);
    gload_lds16(aP + (size_t)(srow + 64) * H + k0 + skc, &sA[2048 + tid * 8]);
    gload_lds16(bP + (size_t)srow * H + k0 + skc, &sB[tid * 8]);
    gload_lds16(bP + (size_t)(srow + 64) * H + k0 + skc, &sB[2048 + tid * 8]);
    __syncthreads();

    bf16x8 aF[4], bF[4];
#pragma unroll
    for (int m = 0; m < 4; ++m)
      aF[m] = *reinterpret_cast<const bf16x8*>(
          &sA[(wr * 64 + m * 16 + (lane & 15)) * BK + (lane >> 4) * 8]);
#pragma unroll
    for (int n = 0; n < 4; ++n)
      bF[n] = *reinterpret_cast<const bf16x8*>(
          &sB[(wc * 64 + n * 16 + (lane & 15)) * BK + (lane >> 4) * 8]);
#pragma unroll
    for (int m = 0; m < 4; ++m)
#pragma unroll
      for (int n = 0; n < 4; ++n)
        acc[m][n] = __builtin_amdgcn_mfma_f32_16x16x32_bf16(aF[m], bF[n], acc[m][n], 0, 0, 0);
    __syncthreads();
  }

  // epilogue: C = acc * (routing . ocs) + bias
#pragma unroll
  for (int m = 0; m < 4; ++m) {
    const int r0 = wr * 64 + m * 16 + ((lane >> 4) << 2);
#pragma unroll
    for (int n = 0; n < 4; ++n) {
      const int c = wc * 64 + n * 16 + (lane & 15);
      const float bz = sBias[c];
#pragma unroll
      for (int j = 0; j < 4; ++j) {
        const int rr = r0 + j;
        float os = 0.f;
#pragma unroll
        for (int e = 0; e < NEXP; ++e) os += sRout[rr][e] * sOcs[e][c];
        C[(size_t)(rowBase + rr) * O + colBase + c] = acc[m][n][j] * os + bz;
      }
    }
  }
}

extern "C" void kernel_launch(void* const* d_in, const int* in_sizes, int n_in,
                              void* d_out, int out_size, void* d_ws, size_t ws_size,
                              hipStream_t stream) {
  const float* x      = (const float*)d_in[0];  // [NTOK][H]
  const float* weight = (const float*)d_in[1];  // [O][H]
  const float* bias   = (const float*)d_in[2];  // [O]
  const float* gate_w = (const float*)d_in[3];  // [E][H]
  const float* ics    = (const float*)d_in[4];  // [E][H]
  const float* ocs    = (const float*)d_in[5];  // [E][O]
  float* out = (float*)d_out;

  char* ws = (char*)d_ws;
  unsigned short* xs = (unsigned short*)ws;                           // 64 MB
  unsigned short* wb = (unsigned short*)(ws + (size_t)NTOK * H * 2);  // 32 MB
  float* routing = (float*)(ws + (size_t)NTOK * H * 2 + (size_t)O * H * 2);  // 256 KB

  sign_kernel<<<4096, 256, 0, stream>>>(weight, wb);
  prep_kernel<<<NTOK, 256, 0, stream>>>(x, gate_w, ics, xs, routing);
  gemm_kernel<<<NBM * NBN, 256, 0, stream>>>(xs, wb, routing, ocs, bias, out);
}

// Round 3
// 965.179 us; speedup vs baseline: 1.0376x; 1.0376x over previous
//
#include <hip/hip_runtime.h>

// ---- problem constants (B=4, S=2048, H=4096, O=4096, E=8) ----
#define NTOK 8192     // B*S
#define H    4096
#define O    4096
#define NEXP 8

typedef __bf16 bf16x8 __attribute__((ext_vector_type(8)));
typedef float  f32x4  __attribute__((ext_vector_type(4)));

typedef const __attribute__((address_space(1))) void* gas_ptr;
typedef __attribute__((address_space(3))) void*       las_ptr;

__device__ __forceinline__ void gload_lds16(const void* g, void* l) {
  __builtin_amdgcn_global_load_lds((gas_ptr)g, (las_ptr)l, 16, 0, 0);
}

__device__ __forceinline__ unsigned short f2bf(float f) {
  unsigned int u = __builtin_bit_cast(unsigned int, f);
  unsigned int r = (u + 0x7FFFu + ((u >> 16) & 1u)) >> 16;  // RNE
  return (unsigned short)r;
}

// ---------------- sign(weight) -> bf16 {+1,-1,0} ----------------
__global__ __launch_bounds__(256) void sign_kernel(const float* __restrict__ w,
                                                   unsigned short* __restrict__ wb) {
  const int n4 = (O * H) / 4;
  int i = blockIdx.x * blockDim.x + threadIdx.x;
  const int stride = gridDim.x * blockDim.x;
  for (; i < n4; i += stride) {
    f32x4 v = __builtin_nontemporal_load(reinterpret_cast<const f32x4*>(w) + i);
    ushort4 o;
    o.x = v.x > 0.f ? 0x3F80u : (v.x < 0.f ? 0xBF80u : 0u);
    o.y = v.y > 0.f ? 0x3F80u : (v.y < 0.f ? 0xBF80u : 0u);
    o.z = v.z > 0.f ? 0x3F80u : (v.z < 0.f ? 0xBF80u : 0u);
    o.w = v.w > 0.f ? 0x3F80u : (v.w < 0.f ? 0xBF80u : 0u);
    reinterpret_cast<ushort4*>(wb)[i] = o;
  }
}

// ---------------- routing + input-scale + bf16 quant ----------------
// one block (256 thr) per 2 token rows: gate_w/ics chunks loaded once, used twice
__global__ __launch_bounds__(256) void prep_kernel(
    const float* __restrict__ x,        // [NTOK][H]
    const float* __restrict__ gw,       // [E][H]
    const float* __restrict__ ics,      // [E][H]
    unsigned short* __restrict__ xs,    // [NTOK][H] bf16 bits
    float* __restrict__ routing) {      // [NTOK][E]
  __shared__ float sRed[2][4 * NEXP];
  __shared__ float sR[2][NEXP];
  const int row0 = blockIdx.x * 2;
  const int tid = threadIdx.x;
  const float* xr0 = x + (size_t)row0 * H;
  const float* xr1 = xr0 + H;

  f32x4 xv0[4], xv1[4];
  float acc0[NEXP], acc1[NEXP];
#pragma unroll
  for (int e = 0; e < NEXP; ++e) { acc0[e] = 0.f; acc1[e] = 0.f; }

#pragma unroll
  for (int i = 0; i < 4; ++i) {
    const int c = (tid + 256 * i) * 4;
    xv0[i] = __builtin_nontemporal_load(reinterpret_cast<const f32x4*>(xr0 + c));
    xv1[i] = __builtin_nontemporal_load(reinterpret_cast<const f32x4*>(xr1 + c));
#pragma unroll
    for (int e = 0; e < NEXP; ++e) {
      f32x4 g = *reinterpret_cast<const f32x4*>(gw + e * H + c);
      acc0[e] += xv0[i].x * g.x + xv0[i].y * g.y + xv0[i].z * g.z + xv0[i].w * g.w;
      acc1[e] += xv1[i].x * g.x + xv1[i].y * g.y + xv1[i].z * g.z + xv1[i].w * g.w;
    }
  }
  // wave64 butterfly reduce
#pragma unroll
  for (int e = 0; e < NEXP; ++e) {
#pragma unroll
    for (int s = 1; s < 64; s <<= 1) {
      acc0[e] += __shfl_xor(acc0[e], s);
      acc1[e] += __shfl_xor(acc1[e], s);
    }
  }
  if ((tid & 63) == 0) {
#pragma unroll
    for (int e = 0; e < NEXP; ++e) {
      sRed[0][(tid >> 6) * NEXP + e] = acc0[e];
      sRed[1][(tid >> 6) * NEXP + e] = acc1[e];
    }
  }
  __syncthreads();
  if (tid < 2) {
    float l[NEXP];
    float mx = -1e30f;
#pragma unroll
    for (int e = 0; e < NEXP; ++e) {
      l[e] = sRed[tid][e] + sRed[tid][NEXP + e] + sRed[tid][2 * NEXP + e] + sRed[tid][3 * NEXP + e];
      mx = fmaxf(mx, l[e]);
    }
    float s = 0.f;
#pragma unroll
    for (int e = 0; e < NEXP; ++e) { l[e] = __expf(l[e] - mx); s += l[e]; }
    const float inv = 1.f / s;
#pragma unroll
    for (int e = 0; e < NEXP; ++e) {
      const float r = l[e] * inv;
      sR[tid][e] = r;
      routing[(size_t)(row0 + tid) * NEXP + e] = r;
    }
  }
  __syncthreads();
  float r0[NEXP], r1[NEXP];
#pragma unroll
  for (int e = 0; e < NEXP; ++e) { r0[e] = sR[0][e]; r1[e] = sR[1][e]; }

#pragma unroll
  for (int i = 0; i < 4; ++i) {
    const int c = (tid + 256 * i) * 4;
    float a0x = 0.f, a0y = 0.f, a0z = 0.f, a0w = 0.f;
    float a1x = 0.f, a1y = 0.f, a1z = 0.f, a1w = 0.f;
#pragma unroll
    for (int e = 0; e < NEXP; ++e) {
      f32x4 g = *reinterpret_cast<const f32x4*>(ics + e * H + c);
      a0x += r0[e] * g.x; a0y += r0[e] * g.y; a0z += r0[e] * g.z; a0w += r0[e] * g.w;
      a1x += r1[e] * g.x; a1y += r1[e] * g.y; a1z += r1[e] * g.z; a1w += r1[e] * g.w;
    }
    ushort4 o0, o1;
    o0.x = f2bf(xv0[i].x * a0x); o0.y = f2bf(xv0[i].y * a0y);
    o0.z = f2bf(xv0[i].z * a0z); o0.w = f2bf(xv0[i].w * a0w);
    o1.x = f2bf(xv1[i].x * a1x); o1.y = f2bf(xv1[i].y * a1y);
    o1.z = f2bf(xv1[i].z * a1z); o1.w = f2bf(xv1[i].w * a1w);
    *reinterpret_cast<ushort4*>(xs + (size_t)row0 * H + c) = o0;
    *reinterpret_cast<ushort4*>(xs + (size_t)(row0 + 1) * H + c) = o1;
  }
}

// ---------------- main GEMM: C = xs @ wb^T, epilogue *out_scale + bias ----------------
// 128x128 tile, BK=32, double-buffered LDS, T3-min schedule, T2 chunk swizzle.
#define TILE 128
#define BK   32
#define NBM  (NTOK / TILE)   // 64
#define NBN  (O / TILE)      // 32

__global__ __launch_bounds__(256) void gemm_kernel(
    const unsigned short* __restrict__ A,   // xs  [NTOK][H] bf16 bits
    const unsigned short* __restrict__ Bw,  // wb  [O][H]   bf16 bits
    const float* __restrict__ routing,      // [NTOK][E]
    const float* __restrict__ ocs,          // [E][O]
    const float* __restrict__ bias,         // [O]
    float* __restrict__ C) {                // [NTOK][O]
  __shared__ __align__(16) unsigned short sA[2][TILE * BK];  // 8 KB x2
  __shared__ __align__(16) unsigned short sB[2][TILE * BK];  // 8 KB x2
  __shared__ float sRout[TILE][NEXP + 1];
  __shared__ float sOcs[NEXP][TILE];
  __shared__ float sBias[TILE];

  const int tid  = threadIdx.x;
  const int lane = tid & 63;
  const int wid  = tid >> 6;
  const int wr   = wid >> 1;   // wave row 0..1
  const int wc   = wid & 1;    // wave col 0..1

  // XCD-aware bijective swizzle (2048 blocks % 8 == 0)
  const int bid = blockIdx.x;
  const int cpx = (NBM * NBN) >> 3;
  const int swz = (bid & 7) * cpx + (bid >> 3);
  const int bm = swz / NBN, bn = swz % NBN;
  const int rowBase = bm * TILE, colBase = bn * TILE;

  // epilogue operands -> LDS (visibility covered by in-loop barriers)
  for (int i = tid; i < TILE * NEXP; i += 256)
    sRout[i >> 3][i & 7] = routing[(size_t)(rowBase + (i >> 3)) * NEXP + (i & 7)];
  for (int i = tid; i < NEXP * TILE; i += 256)
    sOcs[i >> 7][i & 127] = ocs[(size_t)(i >> 7) * O + colBase + (i & 127)];
  if (tid < TILE) sBias[tid] = bias[colBase + tid];

  const f32x4 fzero = {0.f, 0.f, 0.f, 0.f};
  f32x4 acc[4][4];
#pragma unroll
  for (int m = 0; m < 4; ++m)
#pragma unroll
    for (int n = 0; n < 4; ++n) acc[m][n] = fzero;

  const unsigned short* aP = A + (size_t)rowBase * H;
  const unsigned short* bP = Bw + (size_t)colBase * H;
  const int srow = tid >> 2;                        // 0..63 (row; +64 for 2nd half)
  const int key  = (srow >> 1) & 3;                 // swizzle key (same for srow+64)
  const int skc  = (((tid & 3) ^ key) << 3);        // swizzled source k-chunk (elems)

#define STAGE(buf, k0)                                                         \
  do {                                                                         \
    gload_lds16(aP + (size_t)srow * H + (k0) + skc, &sA[buf][tid * 8]);        \
    gload_lds16(aP + (size_t)(srow + 64) * H + (k0) + skc,                     \
                &sA[buf][2048 + tid * 8]);                                     \
    gload_lds16(bP + (size_t)srow * H + (k0) + skc, &sB[buf][tid * 8]);        \
    gload_lds16(bP + (size_t)(srow + 64) * H + (k0) + skc,                     \
                &sB[buf][2048 + tid * 8]);                                     \
  } while (0)

  STAGE(0, 0);
  __syncthreads();  // drains vmcnt(0) before barrier

  int cur = 0;
  for (int k0 = 0; k0 < H; k0 += BK) {
    if (k0 + BK < H) STAGE(cur ^ 1, k0 + BK);  // prefetch next tile (async)

    bf16x8 aF[4], bF[4];
#pragma unroll
    for (int m = 0; m < 4; ++m) {
      const int rr = wr * 64 + m * 16 + (lane & 15);
      const int pos = (((lane >> 4) ^ ((rr >> 1) & 3)) << 3);
      aF[m] = *reinterpret_cast<const bf16x8*>(&sA[cur][rr * BK + pos]);
    }
#pragma unroll
    for (int n = 0; n < 4; ++n) {
      const int rr = wc * 64 + n * 16 + (lane & 15);
      const int pos = (((lane >> 4) ^ ((rr >> 1) & 3)) << 3);
      bF[n] = *reinterpret_cast<const bf16x8*>(&sB[cur][rr * BK + pos]);
    }
#pragma unroll
    for (int m = 0; m < 4; ++m)
#pragma unroll
      for (int n = 0; n < 4; ++n)
        acc[m][n] = __builtin_amdgcn_mfma_f32_16x16x32_bf16(aF[m], bF[n], acc[m][n], 0, 0, 0);

    __syncthreads();  // drains this iter's STAGE + fences buffer reuse
    cur ^= 1;
  }

  // epilogue: C = acc * (routing . ocs) + bias  (nontemporal stores)
#pragma unroll
  for (int m = 0; m < 4; ++m) {
    const int r0 = wr * 64 + m * 16 + ((lane >> 4) << 2);
#pragma unroll
    for (int n = 0; n < 4; ++n) {
      const int c = wc * 64 + n * 16 + (lane & 15);
      const float bz = sBias[c];
#pragma unroll
      for (int j = 0; j < 4; ++j) {
        const int rr = r0 + j;
        float os = 0.f;
#pragma unroll
        for (int e = 0; e < NEXP; ++e) os += sRout[rr][e] * sOcs[e][c];
        __builtin_nontemporal_store(acc[m][n][j] * os + bz,
                                    &C[(size_t)(rowBase + rr) * O + colBase + c]);
      }
    }
  }
#undef STAGE
}

extern "C" void kernel_launch(void* const* d_in, const int* in_sizes, int n_in,
                              void* d_out, int out_size, void* d_ws, size_t ws_size,
                              hipStream_t stream) {
  const float* x      = (const float*)d_in[0];  // [NTOK][H]
  const float* weight = (const float*)d_in[1];  // [O][H]
  const float* bias   = (const float*)d_in[2];  // [O]
  const float* gate_w = (const float*)d_in[3];  // [E][H]
  const float* ics    = (const float*)d_in[4];  // [E][H]
  const float* ocs    = (const float*)d_in[5];  // [E][O]
  float* out = (float*)d_out;

  char* ws = (char*)d_ws;
  unsigned short* xs = (unsigned short*)ws;                           // 64 MB
  unsigned short* wb = (unsigned short*)(ws + (size_t)NTOK * H * 2);  // 32 MB
  float* routing = (float*)(ws + (size_t)NTOK * H * 2 + (size_t)O * H * 2);  // 256 KB

  sign_kernel<<<4096, 256, 0, stream>>>(weight, wb);
  prep_kernel<<<NTOK / 2, 256, 0, stream>>>(x, gate_w, ics, xs, routing);
  gemm_kernel<<<NBM * NBN, 256, 0, stream>>>(xs, wb, routing, ocs, bias, out);
}

// Round 4
// 521.302 us; speedup vs baseline: 1.9211x; 1.8515x over previous
//
#include <hip/hip_runtime.h>

// ---- problem constants (B=4, S=2048, H=4096, O=4096, E=8) ----
#define NTOK 8192     // B*S
#define H    4096
#define O    4096
#define NEXP 8

typedef __bf16 bf16x8 __attribute__((ext_vector_type(8)));
typedef float  f32x4  __attribute__((ext_vector_type(4)));

typedef const __attribute__((address_space(1))) void* gas_ptr;
typedef __attribute__((address_space(3))) void*       las_ptr;

__device__ __forceinline__ void gload_lds16(const void* g, void* l) {
  __builtin_amdgcn_global_load_lds((gas_ptr)g, (las_ptr)l, 16, 0, 0);
}

__device__ __forceinline__ unsigned short f2bf(float f) {
  unsigned int u = __builtin_bit_cast(unsigned int, f);
  unsigned int r = (u + 0x7FFFu + ((u >> 16) & 1u)) >> 16;  // RNE
  return (unsigned short)r;
}

// ---------------- sign(weight) -> bf16 {+1,-1,0} ----------------
__global__ __launch_bounds__(256) void sign_kernel(const float* __restrict__ w,
                                                   unsigned short* __restrict__ wb) {
  const int n4 = (O * H) / 4;
  int i = blockIdx.x * blockDim.x + threadIdx.x;
  const int stride = gridDim.x * blockDim.x;
  for (; i < n4; i += stride) {
    f32x4 v = __builtin_nontemporal_load(reinterpret_cast<const f32x4*>(w) + i);
    ushort4 o;
    o.x = v.x > 0.f ? 0x3F80u : (v.x < 0.f ? 0xBF80u : 0u);
    o.y = v.y > 0.f ? 0x3F80u : (v.y < 0.f ? 0xBF80u : 0u);
    o.z = v.z > 0.f ? 0x3F80u : (v.z < 0.f ? 0xBF80u : 0u);
    o.w = v.w > 0.f ? 0x3F80u : (v.w < 0.f ? 0xBF80u : 0u);
    reinterpret_cast<ushort4*>(wb)[i] = o;
  }
}

// ---------------- routing + input-scale + bf16 quant ----------------
__global__ __launch_bounds__(256) void prep_kernel(
    const float* __restrict__ x,        // [NTOK][H]
    const float* __restrict__ gw,       // [E][H]
    const float* __restrict__ ics,      // [E][H]
    unsigned short* __restrict__ xs,    // [NTOK][H] bf16 bits
    float* __restrict__ routing) {      // [NTOK][E]
  __shared__ float sRed[2][4 * NEXP];
  __shared__ float sR[2][NEXP];
  const int row0 = blockIdx.x * 2;
  const int tid = threadIdx.x;
  const float* xr0 = x + (size_t)row0 * H;
  const float* xr1 = xr0 + H;

  f32x4 xv0[4], xv1[4];
  float acc0[NEXP], acc1[NEXP];
#pragma unroll
  for (int e = 0; e < NEXP; ++e) { acc0[e] = 0.f; acc1[e] = 0.f; }

#pragma unroll
  for (int i = 0; i < 4; ++i) {
    const int c = (tid + 256 * i) * 4;
    xv0[i] = __builtin_nontemporal_load(reinterpret_cast<const f32x4*>(xr0 + c));
    xv1[i] = __builtin_nontemporal_load(reinterpret_cast<const f32x4*>(xr1 + c));
#pragma unroll
    for (int e = 0; e < NEXP; ++e) {
      f32x4 g = *reinterpret_cast<const f32x4*>(gw + e * H + c);
      acc0[e] += xv0[i].x * g.x + xv0[i].y * g.y + xv0[i].z * g.z + xv0[i].w * g.w;
      acc1[e] += xv1[i].x * g.x + xv1[i].y * g.y + xv1[i].z * g.z + xv1[i].w * g.w;
    }
  }
#pragma unroll
  for (int e = 0; e < NEXP; ++e) {
#pragma unroll
    for (int s = 1; s < 64; s <<= 1) {
      acc0[e] += __shfl_xor(acc0[e], s);
      acc1[e] += __shfl_xor(acc1[e], s);
    }
  }
  if ((tid & 63) == 0) {
#pragma unroll
    for (int e = 0; e < NEXP; ++e) {
      sRed[0][(tid >> 6) * NEXP + e] = acc0[e];
      sRed[1][(tid >> 6) * NEXP + e] = acc1[e];
    }
  }
  __syncthreads();
  if (tid < 2) {
    float l[NEXP];
    float mx = -1e30f;
#pragma unroll
    for (int e = 0; e < NEXP; ++e) {
      l[e] = sRed[tid][e] + sRed[tid][NEXP + e] + sRed[tid][2 * NEXP + e] + sRed[tid][3 * NEXP + e];
      mx = fmaxf(mx, l[e]);
    }
    float s = 0.f;
#pragma unroll
    for (int e = 0; e < NEXP; ++e) { l[e] = __expf(l[e] - mx); s += l[e]; }
    const float inv = 1.f / s;
#pragma unroll
    for (int e = 0; e < NEXP; ++e) {
      const float r = l[e] * inv;
      sR[tid][e] = r;
      routing[(size_t)(row0 + tid) * NEXP + e] = r;
    }
  }
  __syncthreads();
  float r0[NEXP], r1[NEXP];
#pragma unroll
  for (int e = 0; e < NEXP; ++e) { r0[e] = sR[0][e]; r1[e] = sR[1][e]; }

#pragma unroll
  for (int i = 0; i < 4; ++i) {
    const int c = (tid + 256 * i) * 4;
    float a0x = 0.f, a0y = 0.f, a0z = 0.f, a0w = 0.f;
    float a1x = 0.f, a1y = 0.f, a1z = 0.f, a1w = 0.f;
#pragma unroll
    for (int e = 0; e < NEXP; ++e) {
      f32x4 g = *reinterpret_cast<const f32x4*>(ics + e * H + c);
      a0x += r0[e] * g.x; a0y += r0[e] * g.y; a0z += r0[e] * g.z; a0w += r0[e] * g.w;
      a1x += r1[e] * g.x; a1y += r1[e] * g.y; a1z += r1[e] * g.z; a1w += r1[e] * g.w;
    }
    ushort4 o0, o1;
    o0.x = f2bf(xv0[i].x * a0x); o0.y = f2bf(xv0[i].y * a0y);
    o0.z = f2bf(xv0[i].z * a0z); o0.w = f2bf(xv0[i].w * a0w);
    o1.x = f2bf(xv1[i].x * a1x); o1.y = f2bf(xv1[i].y * a1y);
    o1.z = f2bf(xv1[i].z * a1z); o1.w = f2bf(xv1[i].w * a1w);
    *reinterpret_cast<ushort4*>(xs + (size_t)row0 * H + c) = o0;
    *reinterpret_cast<ushort4*>(xs + (size_t)(row0 + 1) * H + c) = o1;
  }
}

// ---------------- main GEMM: C = xs @ wb^T ----------------
// 256x256 tile, BK=64, 8 waves (2Mx4N), dbuf LDS, counted-vmcnt pipeline (T3+T4),
// chunk XOR swizzle both-sides (T2, rule 21), setprio around MFMA (T5).
#define BM 256
#define BN 256
#define BK 64
#define NBM (NTOK / BM)   // 32
#define NBN (O / BN)      // 16
#define NKT (H / BK)      // 64
#define ABYTES (BM * BK * 2)       // 32768 (A tile per buffer)
#define TILEB  (2 * ABYTES)        // 65536 (A+B per buffer)
#define EPI_OFF (2 * TILEB)        // 131072
#define SMEM_BYTES (EPI_OFF + BM * NEXP * 4 + NEXP * BN * 4 + BN * 4)  // 148480

__global__ __launch_bounds__(512, 2) void gemm_kernel(
    const unsigned short* __restrict__ A,   // xs  [NTOK][H] bf16 bits
    const unsigned short* __restrict__ Bw,  // wb  [O][H]   bf16 bits
    const float* __restrict__ routing,      // [NTOK][E]
    const float* __restrict__ ocs,          // [E][O]
    const float* __restrict__ bias,         // [O]
    float* __restrict__ C) {                // [NTOK][O]
  extern __shared__ char smem[];
  float* sRout = (float*)(smem + EPI_OFF);                    // [256][8]
  float* sOcs  = (float*)(smem + EPI_OFF + BM * NEXP * 4);    // [8][256]
  float* sBias = (float*)(smem + EPI_OFF + BM * NEXP * 4 + NEXP * BN * 4);

  const int tid  = threadIdx.x;
  const int lane = tid & 63;
  const int wid  = tid >> 6;
  const int wr   = wid >> 2;   // 0..1  (wave rows: 128 each)
  const int wc   = wid & 3;    // 0..3  (wave cols: 64 each)
  const int bh   = wc >> 1;    // B half this wave reads

  // XCD-aware bijective swizzle (512 blocks % 8 == 0)
  const int bid = blockIdx.x;
  const int swz = (bid & 7) * ((NBM * NBN) >> 3) + (bid >> 3);
  const int bm = swz >> 4, bn = swz & 15;  // NBN=16
  const int rowBase = bm * BM, colBase = bn * BN;

  // epilogue operands first (their vmcnt retires before staging loads matter)
  for (int i = tid; i < BM * NEXP; i += 512)
    sRout[i] = routing[(size_t)(rowBase + (i >> 3)) * NEXP + (i & 7)];
  for (int i = tid; i < NEXP * BN; i += 512)
    sOcs[i] = ocs[(size_t)(i >> 8) * O + colBase + (i & 255)];
  if (tid < BN) sBias[tid] = bias[colBase + tid];

  // ---- staging setup: each wave stages EXACTLY the halves it reads ----
  // A-half[wr], quarter wc: rows wr*128 + wc*32 .. +32
  // B-half[bh], quarter wr*2+(wc&1): cols bh*128 + q*32 .. +32
  const int row0A = wr * 128 + wc * 32;
  const int col0B = bh * 128 + (wr * 2 + (wc & 1)) * 32;
  const int sub   = lane >> 3;                       // 0..7 row-in-8
  const int chunk = ((lane & 7) ^ sub) << 3;         // swizzled source chunk (elems)
  const unsigned short* aSrc = A + (size_t)(rowBase + row0A + sub) * H + chunk;
  const unsigned short* bSrc = Bw + (size_t)(colBase + col0B + sub) * H + chunk;

#define STAGE(b, k0)                                                              \
  do {                                                                            \
    _Pragma("unroll") for (int i = 0; i < 4; ++i)                                 \
      gload_lds16(aSrc + (size_t)(i * 8) * H + (k0),                              \
                  smem + (b)*TILEB + (row0A + i * 8) * 128 + lane * 16);          \
    _Pragma("unroll") for (int i = 0; i < 4; ++i)                                 \
      gload_lds16(bSrc + (size_t)(i * 8) * H + (k0),                              \
                  smem + (b)*TILEB + ABYTES + (col0B + i * 8) * 128 + lane * 16); \
  } while (0)

  f32x4 acc[8][4];
#pragma unroll
  for (int m = 0; m < 8; ++m)
#pragma unroll
    for (int n = 0; n < 4; ++n) acc[m][n] = (f32x4){0.f, 0.f, 0.f, 0.f};

  // per-lane LDS read bases; swizzle key folds to p0 = (lane>>4) ^ (lane&7)
  const int p0 = (lane >> 4) ^ (lane & 7);
  const char* aRd = smem + (wr * 128 + (lane & 15)) * 128;
  const char* bRd = smem + ABYTES + (wc * 64 + (lane & 15)) * 128;

  STAGE(0, 0);

  int cur = 0;
  for (int kt = 0; kt < NKT; ++kt) {
    if (kt + 1 < NKT) {
      STAGE(cur ^ 1, (kt + 1) * BK);
      asm volatile("s_waitcnt vmcnt(8)" ::: "memory");  // prev tile's 8 landed; new 8 in flight
    } else {
      asm volatile("s_waitcnt vmcnt(0)" ::: "memory");  // final drain (once)
    }
    __builtin_amdgcn_s_barrier();           // all waves verified their own staged halves
    __builtin_amdgcn_sched_barrier(0);

    const char* aT = aRd + cur * TILEB;
    const char* bT = bRd + cur * TILEB;
#pragma unroll
    for (int kk = 0; kk < 2; ++kk) {
      const int po = (p0 ^ (kk * 4)) * 16;
      bf16x8 aF[8], bF[4];
#pragma unroll
      for (int m = 0; m < 8; ++m)
        aF[m] = *reinterpret_cast<const bf16x8*>(aT + m * 2048 + po);
#pragma unroll
      for (int n = 0; n < 4; ++n)
        bF[n] = *reinterpret_cast<const bf16x8*>(bT + n * 2048 + po);
      __builtin_amdgcn_s_setprio(1);
#pragma unroll
      for (int m = 0; m < 8; ++m)
#pragma unroll
        for (int n = 0; n < 4; ++n)
          acc[m][n] = __builtin_amdgcn_mfma_f32_16x16x32_bf16(aF[m], bF[n], acc[m][n], 0, 0, 0);
      __builtin_amdgcn_s_setprio(0);
    }
    __builtin_amdgcn_sched_barrier(0);
    __builtin_amdgcn_s_barrier();           // all reads of buf cur retired -> next iter may overwrite
    cur ^= 1;
  }
#undef STAGE

  // ---- epilogue: C = acc * (routing . ocs) + bias ----
  float ocsF[4][NEXP];
  float bzF[4];
#pragma unroll
  for (int n = 0; n < 4; ++n) {
    const int c = wc * 64 + n * 16 + (lane & 15);
    bzF[n] = sBias[c];
#pragma unroll
    for (int e = 0; e < NEXP; ++e) ocsF[n][e] = sOcs[e * BN + c];
  }
#pragma unroll
  for (int m = 0; m < 8; ++m) {
    const int rr0 = wr * 128 + m * 16 + ((lane >> 4) << 2);
#pragma unroll
    for (int j = 0; j < 4; ++j) {
      const int rr = rr0 + j;
      f32x4 rA = *reinterpret_cast<const f32x4*>(&sRout[rr * NEXP]);
      f32x4 rB = *reinterpret_cast<const f32x4*>(&sRout[rr * NEXP + 4]);
      float* cRow = C + (size_t)(rowBase + rr) * O + colBase;
#pragma unroll
      for (int n = 0; n < 4; ++n) {
        float os = rA.x * ocsF[n][0] + rA.y * ocsF[n][1] + rA.z * ocsF[n][2] + rA.w * ocsF[n][3] +
                   rB.x * ocsF[n][4] + rB.y * ocsF[n][5] + rB.z * ocsF[n][6] + rB.w * ocsF[n][7];
        cRow[wc * 64 + n * 16 + (lane & 15)] = acc[m][n][j] * os + bzF[n];
      }
    }
  }
}

extern "C" void kernel_launch(void* const* d_in, const int* in_sizes, int n_in,
                              void* d_out, int out_size, void* d_ws, size_t ws_size,
                              hipStream_t stream) {
  const float* x      = (const float*)d_in[0];  // [NTOK][H]
  const float* weight = (const float*)d_in[1];  // [O][H]
  const float* bias   = (const float*)d_in[2];  // [O]
  const float* gate_w = (const float*)d_in[3];  // [E][H]
  const float* ics    = (const float*)d_in[4];  // [E][H]
  const float* ocs    = (const float*)d_in[5];  // [E][O]
  float* out = (float*)d_out;

  char* ws = (char*)d_ws;
  unsigned short* xs = (unsigned short*)ws;                           // 64 MB
  unsigned short* wb = (unsigned short*)(ws + (size_t)NTOK * H * 2);  // 32 MB
  float* routing = (float*)(ws + (size_t)NTOK * H * 2 + (size_t)O * H * 2);  // 256 KB

  (void)hipFuncSetAttribute(reinterpret_cast<const void*>(gemm_kernel),
                            hipFuncAttributeMaxDynamicSharedMemorySize, SMEM_BYTES);

  sign_kernel<<<4096, 256, 0, stream>>>(weight, wb);
  prep_kernel<<<NTOK / 2, 256, 0, stream>>>(x, gate_w, ics, xs, routing);
  gemm_kernel<<<NBM * NBN, 512, SMEM_BYTES, stream>>>(xs, wb, routing, ocs, bias, out);
}